// Round 3
// baseline (589.221 us; speedup 1.0000x reference)
//
#include <hip/hip_runtime.h>
#include <hip/hip_fp16.h>

#define B_ 16
#define C_ 32
#define H_ 256
#define W_ 256
#define HW_ (H_*W_)
#define NPIX ((size_t)B_*C_*HW_)   // 33,554,432

// d_ws layout (bytes):
//  [0, 1MB)            : sigmoid(weights), 4 planes fp32 (up, down, left, right)
//  [1MB, 1MB+16KB)     : wT[128][32] fp32 (transposed conv weights)
//  [1MB+64KB, +64MB)   : uc fp16
//  [.. , +64MB)        : dc fp16
static const size_t WS_SIG = 0;
static const size_t WS_WT  = (size_t)1 << 20;
static const size_t WS_UC  = ((size_t)1 << 20) + (64u << 10);
static const size_t WS_DC  = WS_UC + NPIX * 2;
static const size_t WS_NEED = WS_DC + NPIX * 2;

__global__ __launch_bounds__(256) void k_sigmoid(const float* __restrict__ w,
                                                 float* __restrict__ sw) {
    int i = blockIdx.x * 256 + threadIdx.x;   // 4*65536 = 262144 total
    float x = w[i];
    sw[i] = 1.0f / (1.0f + expf(-x));
}

__global__ __launch_bounds__(256) void k_wT(const float* __restrict__ cw,
                                            float* __restrict__ wT) {
    int i = blockIdx.x * 256 + threadIdx.x;   // 4096 = k*32 + c
    int k = i >> 5, c = i & 31;
    wT[i] = cw[c * 128 + k];
}

// Vertical scans: uc (ascending h), dc (descending h). One thread per (b,c,w) chain.
__global__ __launch_bounds__(256) void k_vscan(const float* __restrict__ inp,
                                               const float* __restrict__ sw,
                                               __half* __restrict__ uc,
                                               __half* __restrict__ dc) {
    int blk = blockIdx.x;           // 1024 blocks: [0,512) = uc, [512,1024) = dc
    int t = threadIdx.x;            // = w
    int bc = blk & 511;             // (b*C + c)
    const float* x = inp + (size_t)bc * HW_ + t;
    if (blk < 512) {
        const float* g = sw + t;                    // w_up plane
        __half* o = uc + (size_t)bc * HW_ + t;
        float cur = x[0];
        o[0] = __float2half(cur);
        #pragma unroll 4
        for (int h = 1; h < H_; ++h) {
            float xv = x[h * W_];
            float gv = g[(h - 1) * W_];
            cur = fmaxf(fmaf(gv, cur, xv), 0.0f);
            o[h * W_] = __float2half(cur);
        }
    } else {
        const float* g = sw + HW_ + t;              // w_down plane
        __half* o = dc + (size_t)bc * HW_ + t;
        float cur = x[(H_ - 1) * W_];
        o[(H_ - 1) * W_] = __float2half(cur);
        #pragma unroll 4
        for (int h = H_ - 2; h >= 0; --h) {
            float xv = x[h * W_];
            float gv = g[(h + 1) * W_];
            cur = fmaxf(fmaf(gv, cur, xv), 0.0f);
            o[h * W_] = __float2half(cur);
        }
    }
}

// Horizontal scans (lc, rc) fused with the 1x1 conv epilogue.
// One workgroup per (b, h). LDS: sx = inp row block (becomes lc in place, fp32,
// XOR-swizzled), src = rc (fp16, swizzled).
__global__ __launch_bounds__(256) void k_hconv(const float* __restrict__ inp,
                                               const float* __restrict__ sw,
                                               const float* __restrict__ wT,
                                               const float* __restrict__ bias,
                                               const __half* __restrict__ uc,
                                               const __half* __restrict__ dc,
                                               float* __restrict__ out) {
    __shared__ float  sx[C_ * W_];    // 32 KB
    __shared__ __half src[C_ * W_];   // 16 KB
    int bid = blockIdx.x;
    int b = bid >> 8;
    int h = bid & 255;
    int t = threadIdx.x;              // = w column in conv phase

    // P1: load inp[b, :, h, :] into LDS (swizzled: addr = c*256 + (w^c))
    const float* ibase = inp + (size_t)b * C_ * HW_ + (size_t)h * W_;
    #pragma unroll 4
    for (int c = 0; c < C_; ++c) {
        sx[(c << 8) | (t ^ c)] = ibase[(size_t)c * HW_ + t];
    }
    __syncthreads();

    const float* gl = sw + 2 * HW_ + h * W_;   // w_left row h
    const float* gr = sw + 3 * HW_ + h * W_;   // w_right row h

    // P2: rc scan, descending w. Threads 0..31 (one per channel).
    if (t < C_) {
        int c = t;
        float cur = sx[(c << 8) | ((W_ - 1) ^ c)];
        src[(c << 8) | ((W_ - 1) ^ c)] = __float2half(cur);
        for (int w = W_ - 2; w >= 0; --w) {
            float xv = sx[(c << 8) | (w ^ c)];
            float gv = gr[w + 1];
            cur = fmaxf(fmaf(gv, cur, xv), 0.0f);
            src[(c << 8) | (w ^ c)] = __float2half(cur);
        }
    }
    __syncthreads();

    // P3: lc scan, ascending w, in place over sx.
    if (t < C_) {
        int c = t;
        float cur = sx[(c << 8) | (0 ^ c)];    // lc[0] = x[0] (no relu)
        for (int w = 1; w < W_; ++w) {
            float xv = sx[(c << 8) | (w ^ c)];
            float gv = gl[w - 1];
            cur = fmaxf(fmaf(gv, cur, xv), 0.0f);
            sx[(c << 8) | (w ^ c)] = cur;
        }
    }
    __syncthreads();

    // P4: conv. ctx k-order: [lc(0..31), rc(32..63), uc(64..95), dc(96..127)]
    float acc[C_];
    #pragma unroll
    for (int c = 0; c < C_; ++c) acc[c] = bias[c];

    const __half* ucp = uc + (size_t)b * C_ * HW_ + (size_t)h * W_ + t;
    const __half* dcp = dc + (size_t)b * C_ * HW_ + (size_t)h * W_ + t;

    for (int cc = 0; cc < C_; ++cc) {
        float vl = sx[(cc << 8) | (t ^ cc)];
        float vr = __half2float(src[(cc << 8) | (t ^ cc)]);
        float vu = __half2float(ucp[(size_t)cc * HW_]);
        float vd = __half2float(dcp[(size_t)cc * HW_]);
        const float* w0 = wT + cc * C_;            // lc weights
        const float* w1 = wT + (32 + cc) * C_;     // rc
        const float* w2 = wT + (64 + cc) * C_;     // uc
        const float* w3 = wT + (96 + cc) * C_;     // dc
        #pragma unroll
        for (int c = 0; c < C_; ++c) {
            float a = acc[c];
            a = fmaf(w0[c], vl, a);
            a = fmaf(w1[c], vr, a);
            a = fmaf(w2[c], vu, a);
            a = fmaf(w3[c], vd, a);
            acc[c] = a;
        }
    }

    float* obase = out + (size_t)b * C_ * HW_ + (size_t)h * W_ + t;
    #pragma unroll
    for (int c = 0; c < C_; ++c) {
        obase[(size_t)c * HW_] = fmaxf(acc[c], 0.0f);
    }
}

extern "C" void kernel_launch(void* const* d_in, const int* in_sizes, int n_in,
                              void* d_out, int out_size, void* d_ws, size_t ws_size,
                              hipStream_t stream) {
    const float* inp     = (const float*)d_in[0];
    const float* weights = (const float*)d_in[1];
    const float* conv_w  = (const float*)d_in[2];
    const float* conv_b  = (const float*)d_in[3];
    float* out = (float*)d_out;

    if (ws_size < WS_NEED) return;   // workspace too small — fail loudly

    char* ws = (char*)d_ws;
    float*  sw  = (float*)(ws + WS_SIG);
    float*  wT  = (float*)(ws + WS_WT);
    __half* uc  = (__half*)(ws + WS_UC);
    __half* dc  = (__half*)(ws + WS_DC);

    // K0a: sigmoid(weights) -> sw  (4*256*256 elems)
    k_sigmoid<<<1024, 256, 0, stream>>>(weights, sw);
    // K0b: transpose conv_w -> wT[128][32]
    k_wT<<<16, 256, 0, stream>>>(conv_w, wT);
    // K1: vertical scans (uc, dc) -> fp16
    k_vscan<<<1024, 256, 0, stream>>>(inp, sw, uc, dc);
    // K2: horizontal scans + fused 1x1 conv -> out
    k_hconv<<<B_ * H_, 256, 0, stream>>>(inp, sw, wT, conv_b, uc, dc, out);
}

// Round 6
// 455.564 us; speedup vs baseline: 1.2934x; 1.2934x over previous
//
#include <hip/hip_runtime.h>
#include <hip/hip_fp16.h>

#define B_ 16
#define C_ 32
#define H_ 256
#define W_ 256
#define HW_ (H_*W_)
#define NPIX ((size_t)B_*C_*HW_)   // 33,554,432

static const size_t WS_SIG = 0;
static const size_t WS_WT  = (size_t)1 << 20;
static const size_t WS_UC  = ((size_t)1 << 20) + (64u << 10);
static const size_t WS_DC  = WS_UC + NPIX * 2;
static const size_t WS_NEED = WS_DC + NPIX * 2;

// LDS swizzle for per-channel row tiles: conflict-free for both
// (a) scan phase: lanes = (c, s) reading w = 32*s + i
// (b) conv phase: lanes = w reading fixed channel cc
#define SWZIDX(c, w) (((c) << 8) | ((w) ^ (((c) & 7) << 2) ^ (((w) >> 6) & 3)))
// gate-row swizzle: lanes with different s read w = 32*s + i (stride 32 -> same
// bank unswizzled); XOR segment into bank bits
#define GSW(w) ((w) ^ ((((w) >> 5) & 7) << 2))

__global__ __launch_bounds__(256) void k_sigmoid(const float* __restrict__ w,
                                                 float* __restrict__ sw) {
    int i = blockIdx.x * 256 + threadIdx.x;
    float x = w[i];
    sw[i] = 1.0f / (1.0f + expf(-x));
}

__global__ __launch_bounds__(256) void k_wT(const float* __restrict__ cw,
                                            float* __restrict__ wT) {
    int i = blockIdx.x * 256 + threadIdx.x;   // 4096 = k*32 + c
    int k = i >> 5, c = i & 31;
    wT[i] = cw[c * 128 + k];
}

// Vertical scans, depth-4 software pipeline: preload next 4 rows before
// computing current 4 so >=8 loads stay in flight across the serial chain.
__global__ __launch_bounds__(256) void k_vscan(const float* __restrict__ inp,
                                               const float* __restrict__ sw,
                                               __half* __restrict__ uc,
                                               __half* __restrict__ dc) {
    int blk = blockIdx.x, t = threadIdx.x, bc = blk & 511;
    const float* xb = inp + (size_t)bc * HW_ + t;
    if (blk < 512) {
        const float* gb = sw + t;                       // up plane
        __half* ob = uc + (size_t)bc * HW_ + t;
        float cur = xb[0];
        ob[0] = __float2half(cur);
        float p0 = xb[1*W_], p1 = xb[2*W_], p2 = xb[3*W_], p3 = xb[4*W_];
        float q0 = gb[0*W_], q1 = gb[1*W_], q2 = gb[2*W_], q3 = gb[3*W_];
        #pragma unroll 1
        for (int h = 1; h <= 245; h += 4) {             // covers h=1..248
            float n0 = xb[(h+4)*W_], n1 = xb[(h+5)*W_];
            float n2 = xb[(h+6)*W_], n3 = xb[(h+7)*W_];
            float m0 = gb[(h+3)*W_], m1 = gb[(h+4)*W_];
            float m2 = gb[(h+5)*W_], m3 = gb[(h+6)*W_];
            cur = fmaxf(fmaf(q0, cur, p0), 0.f); ob[(h+0)*W_] = __float2half(cur);
            cur = fmaxf(fmaf(q1, cur, p1), 0.f); ob[(h+1)*W_] = __float2half(cur);
            cur = fmaxf(fmaf(q2, cur, p2), 0.f); ob[(h+2)*W_] = __float2half(cur);
            cur = fmaxf(fmaf(q3, cur, p3), 0.f); ob[(h+3)*W_] = __float2half(cur);
            p0 = n0; p1 = n1; p2 = n2; p3 = n3;
            q0 = m0; q1 = m1; q2 = m2; q3 = m3;
        }
        // p = x[249..252], q = g[248..251]
        cur = fmaxf(fmaf(q0, cur, p0), 0.f); ob[249*W_] = __float2half(cur);
        cur = fmaxf(fmaf(q1, cur, p1), 0.f); ob[250*W_] = __float2half(cur);
        cur = fmaxf(fmaf(q2, cur, p2), 0.f); ob[251*W_] = __float2half(cur);
        cur = fmaxf(fmaf(q3, cur, p3), 0.f); ob[252*W_] = __float2half(cur);
        for (int h = 253; h < 256; ++h) {
            cur = fmaxf(fmaf(gb[(h-1)*W_], cur, xb[h*W_]), 0.f);
            ob[h*W_] = __float2half(cur);
        }
    } else {
        const float* gb = sw + HW_ + t;                 // down plane
        __half* ob = dc + (size_t)bc * HW_ + t;
        float cur = xb[255*W_];
        ob[255*W_] = __float2half(cur);
        float p0 = xb[254*W_], p1 = xb[253*W_], p2 = xb[252*W_], p3 = xb[251*W_];
        float q0 = gb[255*W_], q1 = gb[254*W_], q2 = gb[253*W_], q3 = gb[252*W_];
        #pragma unroll 1
        for (int r = 254; r >= 10; r -= 4) {            // covers rows 254..7
            float n0 = xb[(r-4)*W_], n1 = xb[(r-5)*W_];
            float n2 = xb[(r-6)*W_], n3 = xb[(r-7)*W_];
            float m0 = gb[(r-3)*W_], m1 = gb[(r-4)*W_];
            float m2 = gb[(r-5)*W_], m3 = gb[(r-6)*W_];
            cur = fmaxf(fmaf(q0, cur, p0), 0.f); ob[(r-0)*W_] = __float2half(cur);
            cur = fmaxf(fmaf(q1, cur, p1), 0.f); ob[(r-1)*W_] = __float2half(cur);
            cur = fmaxf(fmaf(q2, cur, p2), 0.f); ob[(r-2)*W_] = __float2half(cur);
            cur = fmaxf(fmaf(q3, cur, p3), 0.f); ob[(r-3)*W_] = __float2half(cur);
            p0 = n0; p1 = n1; p2 = n2; p3 = n3;
            q0 = m0; q1 = m1; q2 = m2; q3 = m3;
        }
        // p = x[6,5,4,3], q = g[7,6,5,4]
        cur = fmaxf(fmaf(q0, cur, p0), 0.f); ob[6*W_] = __float2half(cur);
        cur = fmaxf(fmaf(q1, cur, p1), 0.f); ob[5*W_] = __float2half(cur);
        cur = fmaxf(fmaf(q2, cur, p2), 0.f); ob[4*W_] = __float2half(cur);
        cur = fmaxf(fmaf(q3, cur, p3), 0.f); ob[3*W_] = __float2half(cur);
        for (int r = 2; r >= 0; --r) {
            cur = fmaxf(fmaf(gb[(r+1)*W_], cur, xb[r*W_]), 0.f);
            ob[r*W_] = __float2half(cur);
        }
    }
}

// Horizontal scans (parallel affine-max segmented scan) fused with 1x1 conv.
// Recurrence out[w] = max(g*out[w-1] + x[w], 0) == f_w(out[w-1]) with
// f = (A,B,C): p -> max(A*p+B, C), closed under composition:
//   (A2,B2,C2)o(A1,B1,C1) = (A2*A1, A2*B1+B2, max(A2*C1+B2, C2))
// thread (c = t>>3, s = t&7) owns segment [32s, 32s+31] of channel c.
__global__ __launch_bounds__(256) void k_hconv(const float* __restrict__ inp,
                                               const float* __restrict__ sw,
                                               const float* __restrict__ wT,
                                               const float* __restrict__ bias,
                                               const __half* __restrict__ uc,
                                               const __half* __restrict__ dc,
                                               float* __restrict__ out) {
    __shared__ float  sx[C_ * W_];    // 32 KB: x, then lc in place
    __shared__ __half src[C_ * W_];   // 16 KB: rc
    __shared__ float  sgl[W_];        // 1 KB: left gates (swizzled)
    __shared__ float  sgr[W_];        // 1 KB: right gates
    int bid = blockIdx.x;
    int b = bid >> 8;
    int h = bid & 255;
    int t = threadIdx.x;
    int lane = t & 63;
    int tm = (t >> 6) & 3;

    // P1: stage x row-block + gate rows
    const float* ibase = inp + (size_t)b * C_ * HW_ + (size_t)h * W_;
    #pragma unroll 8
    for (int c = 0; c < C_; ++c)
        sx[SWZIDX(c, t)] = ibase[(size_t)c * HW_ + t];
    sgl[GSW(t)] = sw[2 * HW_ + h * W_ + t];
    sgr[GSW(t)] = sw[3 * HW_ + h * W_ + t];
    __syncthreads();

    int c = t >> 3, s = t & 7;
    int cbase = c << 8;
    int cm = (c & 7) << 2;
    int sm = (s >> 1) & 3;           // == ((w>>6)&3) for w inside segment
    int ws = s << 5;

    float x0   = sx[cbase | (0 ^ cm)];
    float x255 = sx[cbase | (255 ^ cm ^ 3)];

    // segment compositions (init with first leaf; C=0 after any leaf)
    float lA, lB, lC;
    {
        int w0 = (s == 0) ? 1 : ws;
        lA = sgl[GSW(w0 - 1)];
        lB = sx[cbase | (w0 ^ cm ^ sm)];
        lC = 0.f;
        for (int w = w0 + 1; w <= ws + 31; ++w) {
            float g  = sgl[GSW(w - 1)];
            float xv = sx[cbase | (w ^ cm ^ sm)];
            lA = g * lA;
            lB = fmaf(g, lB, xv);
            lC = fmaxf(fmaf(g, lC, xv), 0.f);
        }
    }
    float rA, rB, rC;
    {
        int w1 = (s == 7) ? 254 : (ws + 31);
        rA = sgr[GSW(w1 + 1)];
        rB = sx[cbase | (w1 ^ cm ^ sm)];
        rC = 0.f;
        for (int w = w1 - 1; w >= ws; --w) {
            float g  = sgr[GSW(w + 1)];
            float xv = sx[cbase | (w ^ cm ^ sm)];
            rA = g * rA;
            rB = fmaf(g, rB, xv);
            rC = fmaxf(fmaf(g, rC, xv), 0.f);
        }
    }

    // Hillis-Steele scans across the 8 segments (in-wave shfl, groups of 8 lanes)
    #pragma unroll
    for (int off = 1; off < 8; off <<= 1) {
        int sl = (s >= off) ? (lane - off) : lane;
        float pA = __shfl(lA, sl), pB = __shfl(lB, sl), pC = __shfl(lC, sl);
        float nA = lA * pA;
        float nB = fmaf(lA, pB, lB);
        float nC = fmaxf(fmaf(lA, pC, lB), lC);
        if (s >= off) { lA = nA; lB = nB; lC = nC; }
        int sr = (s + off <= 7) ? (lane + off) : lane;
        float qA = __shfl(rA, sr), qB = __shfl(rB, sr), qC = __shfl(rC, sr);
        float mA = rA * qA;
        float mB = fmaf(rA, qB, rB);
        float mC = fmaxf(fmaf(rA, qC, rB), rC);
        if (s + off <= 7) { rA = mA; rB = mB; rC = mC; }
    }
    // prefix values entering each segment
    int slm = (s >= 1) ? (lane - 1) : lane;
    float aA = __shfl(lA, slm), aB = __shfl(lB, slm), aC = __shfl(lC, slm);
    float lv = (s == 0) ? x0 : fmaxf(fmaf(aA, x0, aB), aC);
    int srp = (s <= 6) ? (lane + 1) : lane;
    float bA = __shfl(rA, srp), bB = __shfl(rB, srp), bC = __shfl(rC, srp);
    float rv = (s == 7) ? x255 : fmaxf(fmaf(bA, x255, bB), bC);

    // replay RC first (reads sx, writes src)
    {
        float v = rv;
        if (s == 7) src[cbase | (255 ^ cm ^ 3)] = __float2half(x255);
        int wend = (s == 7) ? 254 : (ws + 31);
        for (int w = wend; w >= ws; --w) {
            float xv = sx[cbase | (w ^ cm ^ sm)];
            v = fmaxf(fmaf(sgr[GSW(w + 1)], v, xv), 0.f);
            src[cbase | (w ^ cm ^ sm)] = __float2half(v);
        }
    }
    // replay LC (reads sx, overwrites sx; own segment only, read-before-write)
    {
        float v = lv;
        int wst = (s == 0) ? 1 : ws;
        for (int w = wst; w <= ws + 31; ++w) {
            float xv = sx[cbase | (w ^ cm ^ sm)];
            v = fmaxf(fmaf(sgl[GSW(w - 1)], v, xv), 0.f);
            sx[cbase | (w ^ cm ^ sm)] = v;
        }
    }
    __syncthreads();

    // P4: conv. ctx k-order [lc, rc, uc, dc]
    float acc[C_];
    #pragma unroll
    for (int cc = 0; cc < C_; ++cc) acc[cc] = bias[cc];

    const __half* ucp = uc + (size_t)b * C_ * HW_ + (size_t)h * W_ + t;
    const __half* dcp = dc + (size_t)b * C_ * HW_ + (size_t)h * W_ + t;

    for (int cc = 0; cc < C_; ++cc) {
        int idx = (cc << 8) | (t ^ ((cc & 7) << 2) ^ tm);
        float vl = sx[idx];
        float vr = __half2float(src[idx]);
        float vu = __half2float(ucp[(size_t)cc * HW_]);
        float vd = __half2float(dcp[(size_t)cc * HW_]);
        const float* w0 = wT + cc * C_;
        const float* w1 = wT + (32 + cc) * C_;
        const float* w2 = wT + (64 + cc) * C_;
        const float* w3 = wT + (96 + cc) * C_;
        #pragma unroll
        for (int k = 0; k < C_; ++k) {
            float a = acc[k];
            a = fmaf(w0[k], vl, a);
            a = fmaf(w1[k], vr, a);
            a = fmaf(w2[k], vu, a);
            a = fmaf(w3[k], vd, a);
            acc[k] = a;
        }
    }

    float* obase = out + (size_t)b * C_ * HW_ + (size_t)h * W_ + t;
    #pragma unroll
    for (int k = 0; k < C_; ++k) {
        obase[(size_t)k * HW_] = fmaxf(acc[k], 0.0f);
    }
}

extern "C" void kernel_launch(void* const* d_in, const int* in_sizes, int n_in,
                              void* d_out, int out_size, void* d_ws, size_t ws_size,
                              hipStream_t stream) {
    const float* inp     = (const float*)d_in[0];
    const float* weights = (const float*)d_in[1];
    const float* conv_w  = (const float*)d_in[2];
    const float* conv_b  = (const float*)d_in[3];
    float* out = (float*)d_out;

    if (ws_size < WS_NEED) return;

    char* ws = (char*)d_ws;
    float*  sw  = (float*)(ws + WS_SIG);
    float*  wT  = (float*)(ws + WS_WT);
    __half* uc  = (__half*)(ws + WS_UC);
    __half* dc  = (__half*)(ws + WS_DC);

    k_sigmoid<<<1024, 256, 0, stream>>>(weights, sw);
    k_wT<<<16, 256, 0, stream>>>(conv_w, wT);
    k_vscan<<<1024, 256, 0, stream>>>(inp, sw, uc, dc);
    k_hconv<<<B_ * H_, 256, 0, stream>>>(inp, sw, wT, conv_b, uc, dc, out);
}

// Round 8
// 405.528 us; speedup vs baseline: 1.4530x; 1.1234x over previous
//
#include <hip/hip_runtime.h>
#include <hip/hip_fp16.h>

#define B_ 16
#define C_ 32
#define H_ 256
#define W_ 256
#define HW_ (H_*W_)
#define NPIX ((size_t)B_*C_*HW_)   // 33,554,432

static const size_t WS_SIG = 0;
static const size_t WS_WT  = (size_t)1 << 20;        // packed half2 weights (8 KB)
static const size_t WS_UC  = ((size_t)1 << 20) + (64u << 10);
static const size_t WS_DC  = WS_UC + NPIX * 2;
static const size_t WS_NEED = WS_DC + NPIX * 2;

typedef _Float16 v2h __attribute__((ext_vector_type(2)));

#if defined(__has_builtin)
# if __has_builtin(__builtin_amdgcn_fdot2)
#  define HAVE_FDOT2 1
# endif
#endif

static __device__ __forceinline__ v2h as_v2h(unsigned int u) {
    union { unsigned int i; v2h h; } x; x.i = u; return x.h;
}

// dword-pair LDS swizzle (bank = idx&31): 2-way max for stage / scan / conv phases
#define PIDX(c, w) (((c) << 8) | ((w) ^ (((c) & 7) << 2) ^ (((w) >> 6) & 3)))
#define GSW(w) ((w) ^ ((((w) >> 5) & 7) << 2))

__global__ __launch_bounds__(256) void k_sigmoid(const float* __restrict__ w,
                                                 float* __restrict__ sw) {
    int i = blockIdx.x * 256 + threadIdx.x;
    sw[i] = 1.0f / (1.0f + expf(-w[i]));
}

// pack conv weights as half2: pw[cc*32+k] = {w_lc, w_rc}; pw[1024+cc*32+k] = {w_uc, w_dc}
__global__ __launch_bounds__(256) void k_pack(const float* __restrict__ cw,
                                              unsigned int* __restrict__ pw) {
    int i = blockIdx.x * 256 + threadIdx.x;   // 2048
    int p = i >> 10, cc = (i >> 5) & 31, k = i & 31;
    int base = k * 128 + (p ? 64 : 0) + cc;
    __half lo = __float2half(cw[base]);
    __half hi = __float2half(cw[base + 32]);
    pw[i] = (unsigned int)(*(unsigned short*)&lo) |
            ((unsigned int)(*(unsigned short*)&hi) << 16);
}

// Vertical scans, depth-8 software pipeline (16 loads in flight per wave).
// Block pairing: blocks g*16+r, r<8 -> uc, r>=8 -> dc for bc = g*8 + (r&7):
// uc/dc blocks for the same (b,c) land 8 apart -> same XCD under round-robin.
__global__ __launch_bounds__(256) void k_vscan(const float* __restrict__ inp,
                                               const float* __restrict__ sw,
                                               __half* __restrict__ uc,
                                               __half* __restrict__ dc) {
    int blk = blockIdx.x, t = threadIdx.x;
    int g = blk >> 4, r = blk & 15;
    int dir = r >> 3;
    int bc = g * 8 + (r & 7);
    const float* xb = inp + (size_t)bc * HW_ + t;
    float p[8], q[8], np[8], nq[8];
    if (dir == 0) {
        const float* gb = sw + t;                       // up plane
        __half* ob = uc + (size_t)bc * HW_ + t;
        float cur = xb[0];
        ob[0] = __float2half(cur);
        #pragma unroll
        for (int j = 0; j < 8; ++j) { p[j] = xb[(1+j)*W_]; q[j] = gb[j*W_]; }
        #pragma unroll 1
        for (int h0 = 1; h0 <= 233; h0 += 8) {
            #pragma unroll
            for (int j = 0; j < 8; ++j) {
                np[j] = xb[(h0+8+j)*W_]; nq[j] = gb[(h0+7+j)*W_];
            }
            #pragma unroll
            for (int j = 0; j < 8; ++j) {
                cur = fmaxf(fmaf(q[j], cur, p[j]), 0.f);
                ob[(h0+j)*W_] = __float2half(cur);
            }
            #pragma unroll
            for (int j = 0; j < 8; ++j) { p[j] = np[j]; q[j] = nq[j]; }
        }
        // p = x[241..248], q = g[240..247]
        #pragma unroll
        for (int j = 0; j < 8; ++j) {
            cur = fmaxf(fmaf(q[j], cur, p[j]), 0.f);
            ob[(241+j)*W_] = __float2half(cur);
        }
        for (int h = 249; h < 256; ++h) {
            cur = fmaxf(fmaf(gb[(h-1)*W_], cur, xb[h*W_]), 0.f);
            ob[h*W_] = __float2half(cur);
        }
    } else {
        const float* gb = sw + HW_ + t;                 // down plane
        __half* ob = dc + (size_t)bc * HW_ + t;
        float cur = xb[255*W_];
        ob[255*W_] = __float2half(cur);
        #pragma unroll
        for (int j = 0; j < 8; ++j) { p[j] = xb[(254-j)*W_]; q[j] = gb[(255-j)*W_]; }
        #pragma unroll 1
        for (int r0 = 254; r0 >= 22; r0 -= 8) {
            #pragma unroll
            for (int j = 0; j < 8; ++j) {
                np[j] = xb[(r0-8-j)*W_]; nq[j] = gb[(r0-7-j)*W_];
            }
            #pragma unroll
            for (int j = 0; j < 8; ++j) {
                cur = fmaxf(fmaf(q[j], cur, p[j]), 0.f);
                ob[(r0-j)*W_] = __float2half(cur);
            }
            #pragma unroll
            for (int j = 0; j < 8; ++j) { p[j] = np[j]; q[j] = nq[j]; }
        }
        // p = x[14..7], q = g[15..8] -> rows 14..7
        #pragma unroll
        for (int j = 0; j < 8; ++j) {
            cur = fmaxf(fmaf(q[j], cur, p[j]), 0.f);
            ob[(14-j)*W_] = __float2half(cur);
        }
        for (int rr = 6; rr >= 0; --rr) {
            cur = fmaxf(fmaf(gb[(rr+1)*W_], cur, xb[rr*W_]), 0.f);
            ob[rr*W_] = __float2half(cur);
        }
    }
}

// Horizontal scans (parallel affine-max segmented scan) + 1x1 conv via fdot2.
// LDS pair array: .x half = x (then lc in place), .y half = rc.
__global__ __launch_bounds__(256, 4) void k_hconv(const float* __restrict__ inp,
                                                  const float* __restrict__ sw,
                                                  const unsigned int* __restrict__ pw,
                                                  const float* __restrict__ bias,
                                                  const __half* __restrict__ uc,
                                                  const __half* __restrict__ dc,
                                                  float* __restrict__ out) {
    __shared__ unsigned int spair[C_ * W_];   // 32 KB
    __shared__ float sgl[W_];                 // 1 KB
    __shared__ float sgr[W_];                 // 1 KB
    __half* hp = (__half*)spair;
    int bid = blockIdx.x;
    int b = bid >> 8;
    int h = bid & 255;
    int t = threadIdx.x;
    int lane = t & 63;

    // P1: stage x into .x halves + gate rows
    const float* ibase = inp + (size_t)b * C_ * HW_ + (size_t)h * W_;
    #pragma unroll 8
    for (int c = 0; c < C_; ++c)
        hp[2 * PIDX(c, t)] = __float2half(ibase[(size_t)c * HW_ + t]);
    sgl[GSW(t)] = sw[2 * HW_ + h * W_ + t];
    sgr[GSW(t)] = sw[3 * HW_ + h * W_ + t];
    __syncthreads();

    int c = t >> 3, s = t & 7;
    int cbase = c << 8;
    int cm = (c & 7) << 2;
    int sm = (s >> 1) & 3;           // == ((w>>6)&3) inside segment
    int ws = s << 5;

    float x0   = __half2float(hp[2 * (cbase | (0 ^ cm))]);
    float x255 = __half2float(hp[2 * (cbase | (255 ^ cm ^ 3))]);

    // segment compositions f(p) = max(A*p+B, C)
    float lA, lB, lC;
    {
        int w0 = (s == 0) ? 1 : ws;
        lA = sgl[GSW(w0 - 1)];
        lB = __half2float(hp[2 * (cbase | (w0 ^ cm ^ sm))]);
        lC = 0.f;
        for (int w = w0 + 1; w <= ws + 31; ++w) {
            float gv = sgl[GSW(w - 1)];
            float xv = __half2float(hp[2 * (cbase | (w ^ cm ^ sm))]);
            lA = gv * lA;
            lB = fmaf(gv, lB, xv);
            lC = fmaxf(fmaf(gv, lC, xv), 0.f);
        }
    }
    float rA, rB, rC;
    {
        int w1 = (s == 7) ? 254 : (ws + 31);
        rA = sgr[GSW(w1 + 1)];
        rB = __half2float(hp[2 * (cbase | (w1 ^ cm ^ sm))]);
        rC = 0.f;
        for (int w = w1 - 1; w >= ws; --w) {
            float gv = sgr[GSW(w + 1)];
            float xv = __half2float(hp[2 * (cbase | (w ^ cm ^ sm))]);
            rA = gv * rA;
            rB = fmaf(gv, rB, xv);
            rC = fmaxf(fmaf(gv, rC, xv), 0.f);
        }
    }

    // Hillis-Steele across 8 segments (in-wave shfl)
    #pragma unroll
    for (int off = 1; off < 8; off <<= 1) {
        int sl = (s >= off) ? (lane - off) : lane;
        float pA = __shfl(lA, sl), pB = __shfl(lB, sl), pC = __shfl(lC, sl);
        float nA = lA * pA;
        float nB = fmaf(lA, pB, lB);
        float nC = fmaxf(fmaf(lA, pC, lB), lC);
        if (s >= off) { lA = nA; lB = nB; lC = nC; }
        int sr = (s + off <= 7) ? (lane + off) : lane;
        float qA = __shfl(rA, sr), qB = __shfl(rB, sr), qC = __shfl(rC, sr);
        float mA = rA * qA;
        float mB = fmaf(rA, qB, rB);
        float mC = fmaxf(fmaf(rA, qC, rB), rC);
        if (s + off <= 7) { rA = mA; rB = mB; rC = mC; }
    }
    int slm = (s >= 1) ? (lane - 1) : lane;
    float aA = __shfl(lA, slm), aB = __shfl(lB, slm), aC = __shfl(lC, slm);
    float lv = (s == 0) ? x0 : fmaxf(fmaf(aA, x0, aB), aC);
    int srp = (s <= 6) ? (lane + 1) : lane;
    float bA = __shfl(rA, srp), bB = __shfl(rB, srp), bC = __shfl(rC, srp);
    float rv = (s == 7) ? x255 : fmaxf(fmaf(bA, x255, bB), bC);

    // replay RC (reads .x, writes .y)
    {
        float v = rv;
        if (s == 7) hp[2 * (cbase | (255 ^ cm ^ 3)) + 1] = __float2half(x255);
        int wend = (s == 7) ? 254 : (ws + 31);
        for (int w = wend; w >= ws; --w) {
            int idx = cbase | (w ^ cm ^ sm);
            float xv = __half2float(hp[2 * idx]);
            v = fmaxf(fmaf(sgr[GSW(w + 1)], v, xv), 0.f);
            hp[2 * idx + 1] = __float2half(v);
        }
    }
    // replay LC (reads .x, overwrites .x; own segment, read-before-write)
    {
        float v = lv;
        int wst = (s == 0) ? 1 : ws;
        for (int w = wst; w <= ws + 31; ++w) {
            int idx = cbase | (w ^ cm ^ sm);
            float xv = __half2float(hp[2 * idx]);
            v = fmaxf(fmaf(sgl[GSW(w - 1)], v, xv), 0.f);
            hp[2 * idx] = __float2half(v);
        }
    }
    __syncthreads();

    // P4: conv via dot2. acc[k] += {lc,rc}.{wlc,wrc} + {uc,dc}.{wuc,wdc}
    float acc[C_];
    #pragma unroll
    for (int k = 0; k < C_; ++k) acc[k] = bias[k];

    size_t pixbase = (size_t)b * C_ * HW_ + (size_t)h * W_ + t;
    const unsigned short* ucp = (const unsigned short*)uc + pixbase;
    const unsigned short* dcp = (const unsigned short*)dc + pixbase;
    int tm = (t >> 6) & 3;

    #pragma unroll 4
    for (int cc = 0; cc < C_; ++cc) {
        unsigned int lr = spair[(cc << 8) | (t ^ ((cc & 7) << 2) ^ tm)];
        unsigned int u = ucp[(size_t)cc * HW_];
        unsigned int d = dcp[(size_t)cc * HW_];
        unsigned int ud = u | (d << 16);
        v2h vlr = as_v2h(lr);
        v2h vud = as_v2h(ud);
        const unsigned int* w1 = pw + cc * 32;
        const unsigned int* w2 = pw + 1024 + cc * 32;
#ifdef HAVE_FDOT2
        #pragma unroll
        for (int k = 0; k < C_; ++k) {
            acc[k] = __builtin_amdgcn_fdot2(vlr, as_v2h(w1[k]), acc[k], false);
            acc[k] = __builtin_amdgcn_fdot2(vud, as_v2h(w2[k]), acc[k], false);
        }
#else
        float vl = (float)vlr.x, vr = (float)vlr.y;
        float vu = (float)vud.x, vd = (float)vud.y;
        #pragma unroll
        for (int k = 0; k < C_; ++k) {
            v2h a = as_v2h(w1[k]);
            v2h bb = as_v2h(w2[k]);
            float av = acc[k];
            av = fmaf((float)a.x, vl, av);
            av = fmaf((float)a.y, vr, av);
            av = fmaf((float)bb.x, vu, av);
            av = fmaf((float)bb.y, vd, av);
            acc[k] = av;
        }
#endif
    }

    float* obase = out + pixbase;
    #pragma unroll
    for (int k = 0; k < C_; ++k) {
        obase[(size_t)k * HW_] = fmaxf(acc[k], 0.0f);
    }
}

extern "C" void kernel_launch(void* const* d_in, const int* in_sizes, int n_in,
                              void* d_out, int out_size, void* d_ws, size_t ws_size,
                              hipStream_t stream) {
    const float* inp     = (const float*)d_in[0];
    const float* weights = (const float*)d_in[1];
    const float* conv_w  = (const float*)d_in[2];
    const float* conv_b  = (const float*)d_in[3];
    float* out = (float*)d_out;

    if (ws_size < WS_NEED) return;

    char* ws = (char*)d_ws;
    float*        sw = (float*)(ws + WS_SIG);
    unsigned int* pw = (unsigned int*)(ws + WS_WT);
    __half*       uc = (__half*)(ws + WS_UC);
    __half*       dc = (__half*)(ws + WS_DC);

    k_sigmoid<<<1024, 256, 0, stream>>>(weights, sw);
    k_pack<<<8, 256, 0, stream>>>(conv_w, pw);
    k_vscan<<<1024, 256, 0, stream>>>(inp, sw, uc, dc);
    k_hconv<<<B_ * H_, 256, 0, stream>>>(inp, sw, pw, conv_b, uc, dc, out);
}